// Round 21
// baseline (290.110 us; speedup 1.0000x reference)
//
#include <hip/hip_runtime.h>
#include <stdint.h>

#define BATCH   16
#define NANCH   25200
#define NCLS    80
#define REC     85
#define MAXDET  300
#define TMAX    50
#define NBUCKET 2048
#define FIN     512
#define WREG    400              // per-wave cand region (E~305, +6 sigma)
#define RSTRIDE 12               // words per supp row (10 used, 48B aligned)
#define SUPW    (MAXDET*RSTRIDE) // 3600 words per batch
#define R_KA    12
#define R_KC    16
#define R_KF    16

// output offsets (floats)
#define OFF_PB 0
#define OFF_PS 19200
#define OFF_PL 24000
#define OFF_PK 28800
#define OFF_TB 33600
#define OFF_TS 36800
#define OFF_TL 37600
#define OFF_TV 38400

__device__ __forceinline__ float opaque_f(float x) { asm volatile("" : "+v"(x)); return x; }

// ---- Kernel A: score+label, obj-gated (R19 verbatim body, x12) ----
__global__ __launch_bounds__(256) void kA(const float* __restrict__ logits,
                                          unsigned* __restrict__ confout,
                                          unsigned* __restrict__ labout) {
    const int wid  = (blockIdx.x * 256 + threadIdx.x) >> 6;
    const int lane = threadIdx.x & 63;
    const int t    = lane >> 2;
    const int j    = lane & 3;
    const int a    = wid * 16 + t;
#pragma unroll 1
    for (int rep = 0; rep < R_KA; ++rep) {
        const float obj = logits[(size_t)a * REC + 4];
        unsigned cf = 0u;
        if (obj > 0.8f) {
            const float* cls = logits + (size_t)a * REC + 5 + j * 20;
            float v[20];
#pragma unroll
            for (int i = 0; i < 5; ++i) {
                float4 q = *(const float4*)(cls + 4 * i);
                v[4*i+0] = q.x; v[4*i+1] = q.y; v[4*i+2] = q.z; v[4*i+3] = q.w;
            }
            float m = v[0];
#pragma unroll
            for (int i = 1; i < 20; ++i) m = fmaxf(m, v[i]);
            m = fmaxf(m, __shfl_xor(m, 1));
            m = fmaxf(m, __shfl_xor(m, 2));
            int lc = 255;
#pragma unroll
            for (int i = 0; i < 20; ++i) lc = min(lc, (v[i] == m) ? (j * 20 + i) : 255);
            lc = min(lc, __shfl_xor(lc, 1));
            lc = min(lc, __shfl_xor(lc, 2));
            const float conf = obj * m;
            cf = (conf > 0.8f) ? __float_as_uint(conf) : 0u;
            if (j == 0) labout[a] = (unsigned)lc;
        }
        if (j == 0) confout[a] = cf;
        asm volatile("" ::: "memory");
    }
}

// ---- kCompact: compact-all -> LDS hist -> threshold -> filter -> finv/fcv ----
__global__ __launch_bounds__(1024) void kCompact(const unsigned* __restrict__ confbits,
                                                 unsigned long long* __restrict__ finv,
                                                 int* __restrict__ fcv) {
    __shared__ unsigned long long cand[16 * WREG];
    __shared__ unsigned hist[NBUCKET];
    __shared__ unsigned long long fin[FIN];
    __shared__ int wcnts[16];
    __shared__ int sTb, sCnt;
    const int b = blockIdx.x;
    const int tid = threadIdx.x;
    const int lane = tid & 63;
    const int w = tid >> 6;
    const uint4* cb4 = (const uint4*)(confbits + (size_t)b * NANCH);
#pragma unroll 1
    for (int rep = 0; rep < R_KC; ++rep) {
        for (int i = tid; i < NBUCKET; i += 1024) hist[i] = 0u;
        if (tid == 0) sCnt = 0;
        __syncthreads();
        int wcnt = 0;
        for (int i = tid; i < NANCH / 4; i += 1024) {
            uint4 u = cb4[i];
            unsigned wsv[4] = {u.x, u.y, u.z, u.w};
#pragma unroll
            for (int c = 0; c < 4; ++c) {
                unsigned bits = wsv[c];
                bool pass = (bits != 0u);
                unsigned long long mk = __ballot(pass);
                if (pass) {
                    int p = wcnt + __popcll(mk & ((1ull << lane) - 1ull));
                    if (p < WREG)
                        cand[w * WREG + p] = ((unsigned long long)bits << 32) |
                                             (unsigned)(0xFFFFFFFFu - (unsigned)(i * 4 + c));
                }
                wcnt += (int)__popcll(mk);
            }
        }
        if (lane == 0 && w < 16) wcnts[w] = (wcnt < WREG) ? wcnt : WREG;
        __syncthreads();
        for (int s = tid; s < 16 * WREG; s += 1024) {
            int rw = s / WREG, idx = s - rw * WREG;
            if (idx < wcnts[rw]) {
                unsigned bits = (unsigned)(cand[s] >> 32);
                unsigned bk = (bits - 0x3F4CCCCDu) >> 11;
                if (bk > NBUCKET - 1u) bk = NBUCKET - 1u;
                atomicAdd(&hist[bk], 1u);
            }
        }
        __syncthreads();
        if (tid < 64) {
            const int l = tid;
            unsigned sup = 0u;
            for (int j = 0; j < 32; ++j) sup += hist[l * 32 + j];
            unsigned ss = sup;
            for (int off = 1; off < 64; off <<= 1) {
                unsigned v = __shfl_down(ss, off);
                ss += (l + off < 64) ? v : 0u;
            }
            bool ge = ss >= MAXDET;
            unsigned long long mask = __ballot(ge);
            int sstar = (mask == 0ull) ? 0 : (63 - __clzll(mask));
            unsigned tail = (sstar < 63) ? __shfl(ss, sstar + 1) : 0u;
            unsigned h = (l < 32) ? hist[sstar * 32 + l] : 0u;
            unsigned s2 = h;
            for (int off = 1; off < 32; off <<= 1) {
                unsigned v = __shfl_down(s2, off);
                s2 += (l + off < 32) ? v : 0u;
            }
            bool ge2 = (l < 32) && (s2 + tail >= MAXDET);
            unsigned long long m2 = __ballot(ge2);
            int lstar = (m2 == 0ull) ? 0 : (63 - __clzll(m2));
            if (l == 0) sTb = sstar * 32 + lstar;
        }
        __syncthreads();
        const int tb = sTb;
        for (int s = tid; s < 16 * WREG; s += 1024) {
            int rw = s / WREG, idx = s - rw * WREG;
            bool pass = false;
            unsigned long long k = 0ull;
            if (idx < wcnts[rw]) {
                k = cand[s];
                unsigned bits = (unsigned)(k >> 32);
                unsigned bk = (bits - 0x3F4CCCCDu) >> 11;
                if (bk > NBUCKET - 1u) bk = NBUCKET - 1u;
                pass = ((int)bk >= tb);
            }
            unsigned long long mk = __ballot(pass);
            if (mk) {
                int base = 0;
                if (lane == 0) base = atomicAdd(&sCnt, (int)__popcll(mk));
                base = __shfl(base, 0);
                if (pass) {
                    int p = base + __popcll(mk & ((1ull << lane) - 1ull));
                    if (p < FIN) fin[p] = k;
                }
            }
        }
        __syncthreads();
        int fc = (sCnt < FIN) ? sCnt : FIN;
        if (tid < FIN) finv[(size_t)b * FIN + tid] = (tid < fc) ? fin[tid] : 0ull;
        if (tid == 0) fcv[b * 16] = fc;
        __syncthreads();
        asm volatile("" ::: "memory");
    }
}

// ---- kFinish: fin -> sort -> gather -> outputs + targets ----
__global__ __launch_bounds__(1024) void kFinish(const float* __restrict__ logits,
                                                const unsigned* __restrict__ labels,
                                                const unsigned long long* __restrict__ finv,
                                                const int* __restrict__ fcv,
                                                const float* __restrict__ targets,
                                                const int* __restrict__ tlen,
                                                float* __restrict__ out) {
    __shared__ unsigned long long fin[FIN];
    __shared__ unsigned long long srt[MAXDET];
    const int b = blockIdx.x;
    const int tid = threadIdx.x;
#pragma unroll 1
    for (int rep = 0; rep < R_KF; ++rep) {
        if (tid >= 512 && tid < 512 + TMAX) {
            int t = tid - 512;
            bool is64 = (tlen[1] == 0) && (tlen[3] == 0) && (tlen[5] == 0);
            int len = is64 ? tlen[2 * b] : tlen[b];
            const float* r = targets + ((size_t)b * TMAX + t) * 6;
            float cx = r[0], cy = r[1], wd = r[2], h = r[3], sc = r[4], lb = r[5];
            float hw = opaque_f(wd * 0.5f);
            float hh = opaque_f(h * 0.5f);
            size_t o = (size_t)b * TMAX + t;
            out[OFF_TB + o * 4 + 0] = cx - hw;
            out[OFF_TB + o * 4 + 1] = cy - hh;
            out[OFF_TB + o * 4 + 2] = cx + hw;
            out[OFF_TB + o * 4 + 3] = cy + hh;
            out[OFF_TS + o] = sc;
            out[OFF_TL + o] = (float)(int)lb;
            out[OFF_TV + o] = (t < len) ? 1.0f : 0.0f;
        }
        const int fc = fcv[b * 16];
        if (tid < FIN) fin[tid] = finv[(size_t)b * FIN + tid];
        if (tid < MAXDET) srt[tid] = 0ull;
        __syncthreads();
        if (tid < fc) {
            unsigned long long k = fin[tid];
            int r = 0;
            for (int j = 0; j < fc; ++j) r += (fin[j] > k) ? 1 : 0;
            if (r < MAXDET) srt[r] = k;
        }
        __syncthreads();
        if (tid < MAXDET) {
            unsigned long long key = srt[tid];
            float score = __uint_as_float((unsigned)(key >> 32));
            unsigned n = 0xFFFFFFFFu - (unsigned)(key & 0xFFFFFFFFull);
            if (n >= NANCH) n = 0;
            const size_t ga = (size_t)b * NANCH + n;
            float4 bq = *(const float4*)(logits + ga * REC);
            unsigned lab = labels[ga];
            float hw = opaque_f(bq.z * 0.5f);
            float hh = opaque_f(bq.w * 0.5f);
            float x1 = bq.x - hw, y1 = bq.y - hh, x2 = bq.x + hw, y2 = bq.y + hh;
            size_t o = (size_t)(b * MAXDET + tid);
            out[OFF_PB + o * 4 + 0] = x1;
            out[OFF_PB + o * 4 + 1] = y1;
            out[OFF_PB + o * 4 + 2] = x2;
            out[OFF_PB + o * 4 + 3] = y2;
            out[OFF_PS + o] = score;
            out[OFF_PL + o] = (float)lab;
        }
        __syncthreads();
        asm volatile("" ::: "memory");
    }
}

// ---- kSup: suppression bitmatrix, NEGATED, stride-12, 8 blocks/batch (R19 verbatim) ----
__global__ __launch_bounds__(256) void kSup(const float* __restrict__ out,
                                            unsigned* __restrict__ suppg) {
    __shared__ float4 sb[MAXDET];
    __shared__ float sar[MAXDET];
    const int b = blockIdx.x >> 3;
    const int s = blockIdx.x & 7;
    const int tid = threadIdx.x;
    const int lane = tid & 63;
    const int w = tid >> 6;
    const float4* boxes = (const float4*)(out + OFF_PB) + (size_t)b * MAXDET;
    for (int t = tid; t < MAXDET; t += 256) {
        float4 q = boxes[t];
        sb[t] = q;
        sar[t] = (q.z - q.x) * (q.w - q.y);
    }
    __syncthreads();
    const int i0 = s * 38;
    const int i1 = min(i0 + 38, MAXDET);
    unsigned* sg = suppg + (size_t)b * SUPW;
    for (int i = i0 + w; i < i1; i += 4) {
        float4 bi = sb[i];
        float ai = sar[i];
#pragma unroll
        for (int c = 0; c < 5; ++c) {
            int j = c * 64 + lane;
            bool pass = false;
            if (j < MAXDET && j > i) {
                float4 bj = sb[j];
                float aj = sar[j];
                float ltx = fmaxf(bi.x, bj.x);
                float lty = fmaxf(bi.y, bj.y);
                float rbx = fminf(bi.z, bj.z);
                float rby = fminf(bi.w, bj.w);
                float wx = fmaxf(rbx - ltx, 0.0f);
                float wy = fmaxf(rby - lty, 0.0f);
                float inter = wx * wy;
                float iou = inter / (ai + aj - inter + 1e-9f);
                pass = (iou > 0.4f);
            }
            unsigned long long mk = __ballot(pass);
            if (lane == 0)  sg[i * RSTRIDE + 2 * c]     = ~(unsigned)mk;
            if (lane == 32) sg[i * RSTRIDE + 2 * c + 1] = ~(unsigned)(mk >> 32);
        }
    }
}

// ---- kScan: ctz-driven scan (R19 verbatim) ----
#define PROC(C, KWC)                                                   \
    {                                                                  \
        unsigned todo = KWC;                                           \
        while (todo) {                                                 \
            int i2 = __ffs(todo) - 1;                                  \
            const uint4 a  = s4[(C * 32 + i2) * 3 + 0];                \
            const uint4 bq = s4[(C * 32 + i2) * 3 + 1];                \
            const uint4 cq = s4[(C * 32 + i2) * 3 + 2];                \
            kw0 &= a.x;  kw1 &= a.y;  kw2 &= a.z;  kw3 &= a.w;         \
            kw4 &= bq.x; kw5 &= bq.y; kw6 &= bq.z; kw7 &= bq.w;        \
            kw8 &= cq.x; kw9 &= cq.y;                                  \
            unsigned long long done = ((unsigned long long)2 << i2) - 1ull; \
            todo = KWC & ~(unsigned)done;                              \
        }                                                              \
    }

__global__ __launch_bounds__(512) void kScan(const unsigned* __restrict__ suppg,
                                             float* __restrict__ out) {
    __shared__ __align__(16) unsigned supp[SUPW];
    __shared__ unsigned keepw[10];
    const int b = blockIdx.x;
    const int tid = threadIdx.x;
    const uint4* g4 = (const uint4*)(suppg + (size_t)b * SUPW);
    uint4* l4 = (uint4*)supp;
    for (int t = tid; t < SUPW / 4; t += 512) l4[t] = g4[t];
    __syncthreads();
    if (tid < 64) {
        const uint4* s4 = (const uint4*)supp;
        unsigned kw0 = ~0u, kw1 = ~0u, kw2 = ~0u, kw3 = ~0u, kw4 = ~0u;
        unsigned kw5 = ~0u, kw6 = ~0u, kw7 = ~0u, kw8 = ~0u, kw9 = 0xFFFu;
        PROC(0, kw0) PROC(1, kw1) PROC(2, kw2) PROC(3, kw3) PROC(4, kw4)
        PROC(5, kw5) PROC(6, kw6) PROC(7, kw7) PROC(8, kw8) PROC(9, kw9)
        if (tid == 0) {
            keepw[0] = kw0; keepw[1] = kw1; keepw[2] = kw2; keepw[3] = kw3;
            keepw[4] = kw4; keepw[5] = kw5; keepw[6] = kw6; keepw[7] = kw7;
            keepw[8] = kw8; keepw[9] = kw9;
        }
    }
    __syncthreads();
    if (tid < MAXDET)
        out[OFF_PK + (size_t)b * MAXDET + tid] =
            ((keepw[tid >> 5] >> (tid & 31)) & 1u) ? 1.0f : 0.0f;
}

extern "C" void kernel_launch(void* const* d_in, const int* in_sizes, int n_in,
                              void* d_out, int out_size, void* d_ws, size_t ws_size,
                              hipStream_t stream) {
    const float* logits  = (const float*)d_in[0];
    const float* targets = (const float*)d_in[1];
    const int*   tlen    = (const int*)d_in[2];
    float* out = (float*)d_out;
    char* ws = (char*)d_ws;
    unsigned* confbits = (unsigned*)ws;                                 // 403200 u32
    unsigned* labels   = (unsigned*)(ws + 1612800);                     // 403200 u32
    unsigned long long* finv = (unsigned long long*)(ws + 3225600);     // 16*512 u64
    int* fcv           = (int*)(ws + 3225600 + 65536);                  // 16*16 int
    unsigned* suppg    = (unsigned*)(ws + 3225600 + 65536 + 1024);      // 16*3600 u32

    hipLaunchKernelGGL(kA, dim3(6300), dim3(256), 0, stream, logits, confbits, labels);
    hipLaunchKernelGGL(kCompact, dim3(BATCH), dim3(1024), 0, stream,
                       confbits, finv, fcv);
    hipLaunchKernelGGL(kFinish, dim3(BATCH), dim3(1024), 0, stream,
                       logits, labels, finv, fcv, targets, tlen, out);
    hipLaunchKernelGGL(kSup, dim3(BATCH * 8), dim3(256), 0, stream, out, suppg);
    hipLaunchKernelGGL(kScan, dim3(BATCH), dim3(512), 0, stream, suppg, out);
}

// Round 22
// 145.818 us; speedup vs baseline: 1.9895x; 1.9895x over previous
//
#include <hip/hip_runtime.h>
#include <hip/hip_cooperative_groups.h>
#include <stdint.h>

namespace cg = cooperative_groups;

#define BATCH   16
#define NANCH   25200
#define NCLS    80
#define REC     85
#define MAXDET  300
#define TMAX    50
#define NBUCKET 2048
#define FIN     512
#define FRAGCAP 800              // per-strip cand cap (E~610, sigma~22, +8.5s)
#define RSTRIDE 12               // words per supp row (10 used)
#define SUPW    (MAXDET*RSTRIDE) // 3600 words per batch

// output offsets (floats)
#define OFF_PB 0
#define OFF_PS 19200
#define OFF_PL 24000
#define OFF_PK 28800
#define OFF_TB 33600
#define OFF_TS 36800
#define OFF_TL 37600
#define OFF_TV 38400

__device__ __forceinline__ float opaque_f(float x) { asm volatile("" : "+v"(x)); return x; }

// ---- Kernel A: score+label, obj-gated (R19 verbatim) ----
__global__ __launch_bounds__(256) void kA(const float* __restrict__ logits,
                                          unsigned* __restrict__ confout,
                                          unsigned* __restrict__ labout) {
    const int wid  = (blockIdx.x * 256 + threadIdx.x) >> 6;
    const int lane = threadIdx.x & 63;
    const int t    = lane >> 2;
    const int j    = lane & 3;
    const int a    = wid * 16 + t;
    const float obj = logits[(size_t)a * REC + 4];
    unsigned cf = 0u;
    if (obj > 0.8f) {
        const float* cls = logits + (size_t)a * REC + 5 + j * 20;
        float v[20];
#pragma unroll
        for (int i = 0; i < 5; ++i) {
            float4 q = *(const float4*)(cls + 4 * i);
            v[4*i+0] = q.x; v[4*i+1] = q.y; v[4*i+2] = q.z; v[4*i+3] = q.w;
        }
        float m = v[0];
#pragma unroll
        for (int i = 1; i < 20; ++i) m = fmaxf(m, v[i]);
        m = fmaxf(m, __shfl_xor(m, 1));
        m = fmaxf(m, __shfl_xor(m, 2));
        int lc = 255;
#pragma unroll
        for (int i = 0; i < 20; ++i) lc = min(lc, (v[i] == m) ? (j * 20 + i) : 255);
        lc = min(lc, __shfl_xor(lc, 1));
        lc = min(lc, __shfl_xor(lc, 2));
        const float conf = obj * m;                           // exact: single multiply
        cf = (conf > 0.8f) ? __float_as_uint(conf) : 0u;
        if (j == 0) labout[a] = (unsigned)lc;
    }
    if (j == 0) confout[a] = cf;
}

// ---- kScan PROC macro (R19 verbatim) ----
#define PROC(C, KWC)                                                   \
    {                                                                  \
        unsigned todo = KWC;                                           \
        while (todo) {                                                 \
            int i2 = __ffs(todo) - 1;                                  \
            const uint4 a  = s4[(C * 32 + i2) * 3 + 0];                \
            const uint4 bq = s4[(C * 32 + i2) * 3 + 1];                \
            const uint4 cq = s4[(C * 32 + i2) * 3 + 2];                \
            kw0 &= a.x;  kw1 &= a.y;  kw2 &= a.z;  kw3 &= a.w;         \
            kw4 &= bq.x; kw5 &= bq.y; kw6 &= bq.z; kw7 &= bq.w;        \
            kw8 &= cq.x; kw9 &= cq.y;                                  \
            unsigned long long done = ((unsigned long long)2 << i2) - 1ull; \
            todo = KWC & ~(unsigned)done;                              \
        }                                                              \
    }

// ---- kCoop: 128 blocks x 256 threads, cooperative; 4 phases ----
__global__ __launch_bounds__(256, 1) void kCoop(const float* __restrict__ logits,
                                                const unsigned* __restrict__ confbits,
                                                const unsigned* __restrict__ labels,
                                                unsigned long long* __restrict__ fragg,
                                                int* __restrict__ cntg,
                                                unsigned* __restrict__ suppg,
                                                const float* __restrict__ targets,
                                                const int* __restrict__ tlen,
                                                float* __restrict__ out) {
    cg::grid_group grid = cg::this_grid();
    __shared__ unsigned hist[NBUCKET];                // 8 KB   (phase 2)
    __shared__ unsigned long long fin[FIN];           // 4 KB   (phase 2)
    __shared__ unsigned long long srt[MAXDET];        // 2.4 KB (phase 2)
    __shared__ float4 sb[MAXDET];                     // 4.8 KB (phase 3)
    __shared__ float  sar[MAXDET];                    // 1.2 KB (phase 3)
    __shared__ __align__(16) unsigned supp[SUPW];     // 14.4 KB(phase 4)
    __shared__ unsigned keepw[10];
    __shared__ int scnt, sTb;
    const int blk = blockIdx.x;
    const int b = blk >> 3;
    const int s = blk & 7;
    const int tid = threadIdx.x;
    const int lane = tid & 63;
    const int w = tid >> 6;

    // ======== Phase 1: strip compact (all 128 blocks) ========
    if (tid == 0) scnt = 0;
    __syncthreads();
    {
        const uint4* cb4 = (const uint4*)(confbits + (size_t)b * NANCH);
        const int u40 = s * 788;
        const int u41 = min(6300, u40 + 788);
        unsigned long long* fg = fragg + (size_t)(b * 8 + s) * FRAGCAP;
        // trips(tid) non-increasing -> lane 0 of each wave active whenever any lane is
        for (int i = u40 + tid; i < u41; i += 256) {
            uint4 u = cb4[i];
            unsigned arr[4] = {u.x, u.y, u.z, u.w};
#pragma unroll
            for (int c = 0; c < 4; ++c) {
                unsigned bits = arr[c];
                bool pass = (bits != 0u);
                unsigned long long mk = __ballot(pass);
                if (mk) {
                    int base = 0;
                    if (lane == 0) base = atomicAdd(&scnt, (int)__popcll(mk));
                    base = __shfl(base, 0);
                    if (pass) {
                        int p = base + __popcll(mk & ((1ull << lane) - 1ull));
                        if (p < FRAGCAP)
                            fg[p] = ((unsigned long long)bits << 32) |
                                    (unsigned)(0xFFFFFFFFu - (unsigned)(i * 4 + c));
                    }
                }
            }
        }
        __syncthreads();
        if (tid == 0) cntg[b * 8 + s] = (scnt < FRAGCAP) ? scnt : FRAGCAP;
    }
    __threadfence();
    grid.sync();

    // ======== Phase 2: finisher (s==0); targets (s==1) ========
    if (s == 0) {
        for (int i = tid; i < NBUCKET; i += 256) hist[i] = 0u;
        for (int i = tid; i < MAXDET; i += 256) srt[i] = 0ull;
        if (tid == 0) scnt = 0;
        __syncthreads();
        // sweep 1: hist from the 8 fragments (~4885 keys, L2)
        for (int st = 0; st < 8; ++st) {
            int c = cntg[b * 8 + st];
            const unsigned long long* f = fragg + (size_t)(b * 8 + st) * FRAGCAP;
            for (int i = tid; i < c; i += 256) {
                unsigned bits = (unsigned)(f[i] >> 32);
                unsigned bk = (bits - 0x3F4CCCCDu) >> 11;
                if (bk > NBUCKET - 1u) bk = NBUCKET - 1u;
                atomicAdd(&hist[bk], 1u);
            }
        }
        __syncthreads();
        // threshold bucket tb, wave 0 (verbatim)
        if (tid < 64) {
            const int l = tid;
            unsigned sup = 0u;
            for (int j = 0; j < 32; ++j) sup += hist[l * 32 + j];
            unsigned ss = sup;
            for (int off = 1; off < 64; off <<= 1) {
                unsigned v = __shfl_down(ss, off);
                ss += (l + off < 64) ? v : 0u;
            }
            bool ge = ss >= MAXDET;
            unsigned long long mask = __ballot(ge);
            int sstar = (mask == 0ull) ? 0 : (63 - __clzll(mask));
            unsigned tail = (sstar < 63) ? __shfl(ss, sstar + 1) : 0u;
            unsigned h = (l < 32) ? hist[sstar * 32 + l] : 0u;
            unsigned s2 = h;
            for (int off = 1; off < 32; off <<= 1) {
                unsigned v = __shfl_down(s2, off);
                s2 += (l + off < 32) ? v : 0u;
            }
            bool ge2 = (l < 32) && (s2 + tail >= MAXDET);
            unsigned long long m2 = __ballot(ge2);
            int lstar = (m2 == 0ull) ? 0 : (63 - __clzll(m2));
            if (l == 0) sTb = sstar * 32 + lstar;
        }
        __syncthreads();
        const int tb = sTb;
        // sweep 2: filter >= tb into fin
        for (int st = 0; st < 8; ++st) {
            int c = cntg[b * 8 + st];
            const unsigned long long* f = fragg + (size_t)(b * 8 + st) * FRAGCAP;
            for (int i = tid; i < c; i += 256) {
                unsigned long long k = f[i];
                unsigned bits = (unsigned)(k >> 32);
                unsigned bk = (bits - 0x3F4CCCCDu) >> 11;
                if (bk > NBUCKET - 1u) bk = NBUCKET - 1u;
                bool pass = ((int)bk >= tb);
                unsigned long long mk = __ballot(pass);
                if (mk) {
                    int base = 0;
                    if (lane == 0) base = atomicAdd(&scnt, (int)__popcll(mk));
                    base = __shfl(base, 0);
                    if (pass) {
                        int p = base + __popcll(mk & ((1ull << lane) - 1ull));
                        if (p < FIN) fin[p] = k;
                    }
                }
            }
        }
        __syncthreads();
        const int fc = (scnt < FIN) ? scnt : FIN;
        // rank-scatter sort (order-independent; keys unique)
        for (int i = tid; i < fc; i += 256) {
            unsigned long long k = fin[i];
            int r = 0;
            for (int j = 0; j < fc; ++j) r += (fin[j] > k) ? 1 : 0;
            if (r < MAXDET) srt[r] = k;
        }
        __syncthreads();
        // gather top-300 (verbatim)
        for (int i = tid; i < MAXDET; i += 256) {
            unsigned long long key = srt[i];
            float score = __uint_as_float((unsigned)(key >> 32));
            unsigned n = 0xFFFFFFFFu - (unsigned)(key & 0xFFFFFFFFull);
            if (n >= NANCH) n = 0;
            const size_t ga = (size_t)b * NANCH + n;
            float4 bq = *(const float4*)(logits + ga * REC);
            unsigned lab = labels[ga];
            float hw = opaque_f(bq.z * 0.5f);  // block FMA contraction: match XLA
            float hh = opaque_f(bq.w * 0.5f);
            float x1 = bq.x - hw, y1 = bq.y - hh, x2 = bq.x + hw, y2 = bq.y + hh;
            size_t o = (size_t)(b * MAXDET + i);
            out[OFF_PB + o * 4 + 0] = x1;
            out[OFF_PB + o * 4 + 1] = y1;
            out[OFF_PB + o * 4 + 2] = x2;
            out[OFF_PB + o * 4 + 3] = y2;
            out[OFF_PS + o] = score;
            out[OFF_PL + o] = (float)lab;
        }
    } else if (s == 1) {
        // targets for batch b (verbatim math)
        if (tid < TMAX) {
            int t = tid;
            bool is64 = (tlen[1] == 0) && (tlen[3] == 0) && (tlen[5] == 0);
            int len = is64 ? tlen[2 * b] : tlen[b];
            const float* r = targets + ((size_t)b * TMAX + t) * 6;
            float cx = r[0], cy = r[1], wd = r[2], h = r[3], sc = r[4], lb = r[5];
            float hw = opaque_f(wd * 0.5f);
            float hh = opaque_f(h * 0.5f);
            size_t o = (size_t)b * TMAX + t;
            out[OFF_TB + o * 4 + 0] = cx - hw;
            out[OFF_TB + o * 4 + 1] = cy - hh;
            out[OFF_TB + o * 4 + 2] = cx + hw;
            out[OFF_TB + o * 4 + 3] = cy + hh;
            out[OFF_TS + o] = sc;
            out[OFF_TL + o] = (float)(int)lb;
            out[OFF_TV + o] = (t < len) ? 1.0f : 0.0f;
        }
    }
    __threadfence();
    grid.sync();

    // ======== Phase 3: supp matrix, NEGATED, stride-12 (all 128 blocks) ========
    {
        const float4* boxes = (const float4*)(out + OFF_PB) + (size_t)b * MAXDET;
        for (int t = tid; t < MAXDET; t += 256) {
            float4 q = boxes[t];
            sb[t] = q;
            sar[t] = (q.z - q.x) * (q.w - q.y);   // same floats as reference area
        }
        __syncthreads();
        const int i0 = s * 38;
        const int i1 = min(i0 + 38, MAXDET);
        unsigned* sg = suppg + (size_t)b * SUPW;
        for (int i = i0 + w; i < i1; i += 4) {
            float4 bi = sb[i];
            float ai = sar[i];
#pragma unroll
            for (int c = 0; c < 5; ++c) {
                int j = c * 64 + lane;
                bool pass = false;
                if (j < MAXDET && j > i) {
                    float4 bj = sb[j];
                    float aj = sar[j];
                    float ltx = fmaxf(bi.x, bj.x);
                    float lty = fmaxf(bi.y, bj.y);
                    float rbx = fminf(bi.z, bj.z);
                    float rby = fminf(bi.w, bj.w);
                    float wx = fmaxf(rbx - ltx, 0.0f);
                    float wy = fmaxf(rby - lty, 0.0f);
                    float inter = wx * wy;
                    float iou = inter / (ai + aj - inter + 1e-9f);  // left-to-right
                    pass = (iou > 0.4f);
                }
                unsigned long long mk = __ballot(pass);
                if (lane == 0)  sg[i * RSTRIDE + 2 * c]     = ~(unsigned)mk;
                if (lane == 32) sg[i * RSTRIDE + 2 * c + 1] = ~(unsigned)(mk >> 32);
            }
        }
    }
    __threadfence();
    grid.sync();

    // ======== Phase 4: ctz scan (s==0 blocks) ========
    if (s == 0) {
        const uint4* g4 = (const uint4*)(suppg + (size_t)b * SUPW);
        uint4* l4 = (uint4*)supp;
        for (int t = tid; t < SUPW / 4; t += 256) l4[t] = g4[t];
        __syncthreads();
        if (tid < 64) {
            const uint4* s4 = (const uint4*)supp;
            unsigned kw0 = ~0u, kw1 = ~0u, kw2 = ~0u, kw3 = ~0u, kw4 = ~0u;
            unsigned kw5 = ~0u, kw6 = ~0u, kw7 = ~0u, kw8 = ~0u, kw9 = 0xFFFu;
            PROC(0, kw0) PROC(1, kw1) PROC(2, kw2) PROC(3, kw3) PROC(4, kw4)
            PROC(5, kw5) PROC(6, kw6) PROC(7, kw7) PROC(8, kw8) PROC(9, kw9)
            if (tid == 0) {
                keepw[0] = kw0; keepw[1] = kw1; keepw[2] = kw2; keepw[3] = kw3;
                keepw[4] = kw4; keepw[5] = kw5; keepw[6] = kw6; keepw[7] = kw7;
                keepw[8] = kw8; keepw[9] = kw9;
            }
        }
        __syncthreads();
        for (int i = tid; i < MAXDET; i += 256)
            out[OFF_PK + (size_t)b * MAXDET + i] =
                ((keepw[i >> 5] >> (i & 31)) & 1u) ? 1.0f : 0.0f;
    }
}

extern "C" void kernel_launch(void* const* d_in, const int* in_sizes, int n_in,
                              void* d_out, int out_size, void* d_ws, size_t ws_size,
                              hipStream_t stream) {
    const float* logits  = (const float*)d_in[0];
    const float* targets = (const float*)d_in[1];
    const int*   tlen    = (const int*)d_in[2];
    float* out = (float*)d_out;
    char* ws = (char*)d_ws;
    unsigned* confbits = (unsigned*)ws;                                 // 1.613 MB
    unsigned* labels   = (unsigned*)(ws + 1612800);                     // 1.613 MB
    unsigned long long* fragg = (unsigned long long*)(ws + 3225600);    // 128*800 u64
    int* cntg          = (int*)(ws + 3225600 + 819200);                 // 128 int
    unsigned* suppg    = (unsigned*)(ws + 3225600 + 819200 + 512);      // 16*3600 u32

    hipLaunchKernelGGL(kA, dim3(6300), dim3(256), 0, stream, logits, confbits, labels);

    void* args[] = {(void*)&logits, (void*)&confbits, (void*)&labels,
                    (void*)&fragg, (void*)&cntg, (void*)&suppg,
                    (void*)&targets, (void*)&tlen, (void*)&out};
    hipLaunchCooperativeKernel((void*)kCoop, dim3(128), dim3(256), args, 0, stream);
}

// Round 23
// 88.673 us; speedup vs baseline: 3.2717x; 1.6445x over previous
//
#include <hip/hip_runtime.h>
#include <stdint.h>

#define BATCH   16
#define NANCH   25200
#define NCLS    80
#define REC     85
#define MAXDET  300
#define TMAX    50
#define NBUCKET 2048
#define FIN     512
#define FRAGCAP 800              // per-strip cand cap (E~610, sigma~22, +8.5s)
#define RSTRIDE 12               // words per supp row (10 used)
#define SUPW    (MAXDET*RSTRIDE) // 3600 words per batch

// output offsets (floats)
#define OFF_PB 0
#define OFF_PS 19200
#define OFF_PL 24000
#define OFF_PK 28800
#define OFF_TB 33600
#define OFF_TS 36800
#define OFF_TL 37600
#define OFF_TV 38400

__device__ __forceinline__ float opaque_f(float x) { asm volatile("" : "+v"(x)); return x; }

__device__ __forceinline__ void sig_add(int* p) {
    __threadfence();
    __hip_atomic_fetch_add(p, 1, __ATOMIC_RELEASE, __HIP_MEMORY_SCOPE_AGENT);
}
__device__ __forceinline__ void sig_set(int* p) {
    __threadfence();
    __hip_atomic_store(p, 1, __ATOMIC_RELEASE, __HIP_MEMORY_SCOPE_AGENT);
}
__device__ __forceinline__ void spin_until(int* p, int v) {
    while (__hip_atomic_load(p, __ATOMIC_ACQUIRE, __HIP_MEMORY_SCOPE_AGENT) < v)
        __builtin_amdgcn_s_sleep(8);
}

// ---- Kernel A: score+label, obj-gated (R19 verbatim) + flag zeroing ----
__global__ __launch_bounds__(256) void kA(const float* __restrict__ logits,
                                          unsigned* __restrict__ confout,
                                          unsigned* __restrict__ labout,
                                          int* __restrict__ flags) {
    if (blockIdx.x == 6299 && threadIdx.x < 48) flags[threadIdx.x] = 0;  // zero sync flags
    const int wid  = (blockIdx.x * 256 + threadIdx.x) >> 6;
    const int lane = threadIdx.x & 63;
    const int t    = lane >> 2;
    const int j    = lane & 3;
    const int a    = wid * 16 + t;
    const float obj = logits[(size_t)a * REC + 4];
    unsigned cf = 0u;
    if (obj > 0.8f) {
        const float* cls = logits + (size_t)a * REC + 5 + j * 20;
        float v[20];
#pragma unroll
        for (int i = 0; i < 5; ++i) {
            float4 q = *(const float4*)(cls + 4 * i);
            v[4*i+0] = q.x; v[4*i+1] = q.y; v[4*i+2] = q.z; v[4*i+3] = q.w;
        }
        float m = v[0];
#pragma unroll
        for (int i = 1; i < 20; ++i) m = fmaxf(m, v[i]);
        m = fmaxf(m, __shfl_xor(m, 1));
        m = fmaxf(m, __shfl_xor(m, 2));
        int lc = 255;
#pragma unroll
        for (int i = 0; i < 20; ++i) lc = min(lc, (v[i] == m) ? (j * 20 + i) : 255);
        lc = min(lc, __shfl_xor(lc, 1));
        lc = min(lc, __shfl_xor(lc, 2));
        const float conf = obj * m;                           // exact: single multiply
        cf = (conf > 0.8f) ? __float_as_uint(conf) : 0u;
        if (j == 0) labout[a] = (unsigned)lc;
    }
    if (j == 0) confout[a] = cf;
}

// ---- ctz-scan PROC macro (R19 verbatim) ----
#define PROC(C, KWC)                                                   \
    {                                                                  \
        unsigned todo = KWC;                                           \
        while (todo) {                                                 \
            int i2 = __ffs(todo) - 1;                                  \
            const uint4 a  = s4[(C * 32 + i2) * 3 + 0];                \
            const uint4 bq = s4[(C * 32 + i2) * 3 + 1];                \
            const uint4 cq = s4[(C * 32 + i2) * 3 + 2];                \
            kw0 &= a.x;  kw1 &= a.y;  kw2 &= a.z;  kw3 &= a.w;         \
            kw4 &= bq.x; kw5 &= bq.y; kw6 &= bq.z; kw7 &= bq.w;        \
            kw8 &= cq.x; kw9 &= cq.y;                                  \
            unsigned long long done = ((unsigned long long)2 << i2) - 1ull; \
            todo = KWC & ~(unsigned)done;                              \
        }                                                              \
    }

// ---- kMega: 128 co-resident blocks, flag-synced phases ----
__global__ __launch_bounds__(256, 1) void kMega(const float* __restrict__ logits,
                                                const unsigned* __restrict__ confbits,
                                                const unsigned* __restrict__ labels,
                                                unsigned long long* __restrict__ fragg,
                                                int* __restrict__ cntg,
                                                unsigned* __restrict__ suppg,
                                                int* __restrict__ flags,
                                                const float* __restrict__ targets,
                                                const int* __restrict__ tlen,
                                                float* __restrict__ out) {
    __shared__ unsigned hist[NBUCKET];
    __shared__ unsigned long long fin[FIN];
    __shared__ unsigned long long srt[MAXDET];
    __shared__ float4 sb[MAXDET];
    __shared__ float  sar[MAXDET];
    __shared__ __align__(16) unsigned supp[SUPW];
    __shared__ unsigned keepw[10];
    __shared__ int scnt, sTb;
    int* stripDone = flags;            // [16]
    int* boxReady  = flags + 16;       // [16]
    int* suppDone  = flags + 32;       // [16]
    const int blk = blockIdx.x;
    const int b = blk >> 3;
    const int s = blk & 7;
    const int tid = threadIdx.x;
    const int lane = tid & 63;
    const int w = tid >> 6;

    // ======== Phase 1: strip compact ========
    if (tid == 0) scnt = 0;
    __syncthreads();
    {
        const uint4* cb4 = (const uint4*)(confbits + (size_t)b * NANCH);
        const int u40 = s * 788;
        const int u41 = min(6300, u40 + 788);
        unsigned long long* fg = fragg + (size_t)(b * 8 + s) * FRAGCAP;
        for (int i = u40 + tid; i < u41; i += 256) {
            uint4 u = cb4[i];
            unsigned arr[4] = {u.x, u.y, u.z, u.w};
#pragma unroll
            for (int c = 0; c < 4; ++c) {
                unsigned bits = arr[c];
                bool pass = (bits != 0u);
                unsigned long long mk = __ballot(pass);
                if (mk) {
                    int base = 0;
                    if (lane == 0) base = atomicAdd(&scnt, (int)__popcll(mk));
                    base = __shfl(base, 0);
                    if (pass) {
                        int p = base + __popcll(mk & ((1ull << lane) - 1ull));
                        if (p < FRAGCAP)
                            fg[p] = ((unsigned long long)bits << 32) |
                                    (unsigned)(0xFFFFFFFFu - (unsigned)(i * 4 + c));
                    }
                }
            }
        }
        __syncthreads();
        if (tid == 0) {
            cntg[b * 8 + s] = (scnt < FRAGCAP) ? scnt : FRAGCAP;
            sig_add(&stripDone[b]);
        }
    }

    // ======== Phase 2: finisher (s==0) / targets (s==1) ========
    if (s == 0) {
        if (tid == 0) spin_until(&stripDone[b], 8);
        __syncthreads();
        for (int i = tid; i < NBUCKET; i += 256) hist[i] = 0u;
        for (int i = tid; i < MAXDET; i += 256) srt[i] = 0ull;
        if (tid == 0) scnt = 0;
        __syncthreads();
        for (int st = 0; st < 8; ++st) {
            int c = cntg[b * 8 + st];
            const unsigned long long* f = fragg + (size_t)(b * 8 + st) * FRAGCAP;
            for (int i = tid; i < c; i += 256) {
                unsigned bits = (unsigned)(f[i] >> 32);
                unsigned bk = (bits - 0x3F4CCCCDu) >> 11;
                if (bk > NBUCKET - 1u) bk = NBUCKET - 1u;
                atomicAdd(&hist[bk], 1u);
            }
        }
        __syncthreads();
        if (tid < 64) {
            const int l = tid;
            unsigned sup = 0u;
            for (int j = 0; j < 32; ++j) sup += hist[l * 32 + j];
            unsigned ss = sup;
            for (int off = 1; off < 64; off <<= 1) {
                unsigned v = __shfl_down(ss, off);
                ss += (l + off < 64) ? v : 0u;
            }
            bool ge = ss >= MAXDET;
            unsigned long long mask = __ballot(ge);
            int sstar = (mask == 0ull) ? 0 : (63 - __clzll(mask));
            unsigned tail = (sstar < 63) ? __shfl(ss, sstar + 1) : 0u;
            unsigned h = (l < 32) ? hist[sstar * 32 + l] : 0u;
            unsigned s2 = h;
            for (int off = 1; off < 32; off <<= 1) {
                unsigned v = __shfl_down(s2, off);
                s2 += (l + off < 32) ? v : 0u;
            }
            bool ge2 = (l < 32) && (s2 + tail >= MAXDET);
            unsigned long long m2 = __ballot(ge2);
            int lstar = (m2 == 0ull) ? 0 : (63 - __clzll(m2));
            if (l == 0) sTb = sstar * 32 + lstar;
        }
        __syncthreads();
        const int tb = sTb;
        for (int st = 0; st < 8; ++st) {
            int c = cntg[b * 8 + st];
            const unsigned long long* f = fragg + (size_t)(b * 8 + st) * FRAGCAP;
            for (int i = tid; i < c; i += 256) {
                unsigned long long k = f[i];
                unsigned bits = (unsigned)(k >> 32);
                unsigned bk = (bits - 0x3F4CCCCDu) >> 11;
                if (bk > NBUCKET - 1u) bk = NBUCKET - 1u;
                bool pass = ((int)bk >= tb);
                unsigned long long mk = __ballot(pass);
                if (mk) {
                    int base = 0;
                    if (lane == 0) base = atomicAdd(&scnt, (int)__popcll(mk));
                    base = __shfl(base, 0);
                    if (pass) {
                        int p = base + __popcll(mk & ((1ull << lane) - 1ull));
                        if (p < FIN) fin[p] = k;
                    }
                }
            }
        }
        __syncthreads();
        const int fc = (scnt < FIN) ? scnt : FIN;
        for (int i = tid; i < fc; i += 256) {
            unsigned long long k = fin[i];
            int r = 0;
            for (int j = 0; j < fc; ++j) r += (fin[j] > k) ? 1 : 0;
            if (r < MAXDET) srt[r] = k;
        }
        __syncthreads();
        for (int i = tid; i < MAXDET; i += 256) {
            unsigned long long key = srt[i];
            float score = __uint_as_float((unsigned)(key >> 32));
            unsigned n = 0xFFFFFFFFu - (unsigned)(key & 0xFFFFFFFFull);
            if (n >= NANCH) n = 0;
            const size_t ga = (size_t)b * NANCH + n;
            float4 bq = *(const float4*)(logits + ga * REC);
            unsigned lab = labels[ga];
            float hw = opaque_f(bq.z * 0.5f);  // block FMA contraction: match XLA
            float hh = opaque_f(bq.w * 0.5f);
            float x1 = bq.x - hw, y1 = bq.y - hh, x2 = bq.x + hw, y2 = bq.y + hh;
            size_t o = (size_t)(b * MAXDET + i);
            out[OFF_PB + o * 4 + 0] = x1;
            out[OFF_PB + o * 4 + 1] = y1;
            out[OFF_PB + o * 4 + 2] = x2;
            out[OFF_PB + o * 4 + 3] = y2;
            out[OFF_PS + o] = score;
            out[OFF_PL + o] = (float)lab;
        }
        __syncthreads();
        if (tid == 0) sig_set(&boxReady[b]);
    } else if (s == 1) {
        if (tid < TMAX) {
            int t = tid;
            bool is64 = (tlen[1] == 0) && (tlen[3] == 0) && (tlen[5] == 0);
            int len = is64 ? tlen[2 * b] : tlen[b];
            const float* r = targets + ((size_t)b * TMAX + t) * 6;
            float cx = r[0], cy = r[1], wd = r[2], h = r[3], sc = r[4], lb = r[5];
            float hw = opaque_f(wd * 0.5f);
            float hh = opaque_f(h * 0.5f);
            size_t o = (size_t)b * TMAX + t;
            out[OFF_TB + o * 4 + 0] = cx - hw;
            out[OFF_TB + o * 4 + 1] = cy - hh;
            out[OFF_TB + o * 4 + 2] = cx + hw;
            out[OFF_TB + o * 4 + 3] = cy + hh;
            out[OFF_TS + o] = sc;
            out[OFF_TL + o] = (float)(int)lb;
            out[OFF_TV + o] = (t < len) ? 1.0f : 0.0f;
        }
    }

    // ======== Phase 3: supp strips (all 128 blocks) ========
    if (tid == 0) spin_until(&boxReady[b], 1);
    __syncthreads();
    {
        const float4* boxes = (const float4*)(out + OFF_PB) + (size_t)b * MAXDET;
        for (int t = tid; t < MAXDET; t += 256) {
            float4 q = boxes[t];
            sb[t] = q;
            sar[t] = (q.z - q.x) * (q.w - q.y);   // same floats as reference area
        }
        __syncthreads();
        const int i0 = s * 38;
        const int i1 = min(i0 + 38, MAXDET);
        unsigned* sg = suppg + (size_t)b * SUPW;
        for (int i = i0 + w; i < i1; i += 4) {
            float4 bi = sb[i];
            float ai = sar[i];
#pragma unroll
            for (int c = 0; c < 5; ++c) {
                int j = c * 64 + lane;
                bool pass = false;
                if (j < MAXDET && j > i) {
                    float4 bj = sb[j];
                    float aj = sar[j];
                    float ltx = fmaxf(bi.x, bj.x);
                    float lty = fmaxf(bi.y, bj.y);
                    float rbx = fminf(bi.z, bj.z);
                    float rby = fminf(bi.w, bj.w);
                    float wx = fmaxf(rbx - ltx, 0.0f);
                    float wy = fmaxf(rby - lty, 0.0f);
                    float inter = wx * wy;
                    float iou = inter / (ai + aj - inter + 1e-9f);  // left-to-right
                    pass = (iou > 0.4f);
                }
                unsigned long long mk = __ballot(pass);
                if (lane == 0)  sg[i * RSTRIDE + 2 * c]     = ~(unsigned)mk;
                if (lane == 32) sg[i * RSTRIDE + 2 * c + 1] = ~(unsigned)(mk >> 32);
            }
        }
        __syncthreads();
        if (tid == 0) sig_add(&suppDone[b]);
    }

    // ======== Phase 4: ctz scan (s==0) ========
    if (s == 0) {
        if (tid == 0) spin_until(&suppDone[b], 8);
        __syncthreads();
        const uint4* g4 = (const uint4*)(suppg + (size_t)b * SUPW);
        uint4* l4 = (uint4*)supp;
        for (int t = tid; t < SUPW / 4; t += 256) l4[t] = g4[t];
        __syncthreads();
        if (tid < 64) {
            const uint4* s4 = (const uint4*)supp;
            unsigned kw0 = ~0u, kw1 = ~0u, kw2 = ~0u, kw3 = ~0u, kw4 = ~0u;
            unsigned kw5 = ~0u, kw6 = ~0u, kw7 = ~0u, kw8 = ~0u, kw9 = 0xFFFu;
            PROC(0, kw0) PROC(1, kw1) PROC(2, kw2) PROC(3, kw3) PROC(4, kw4)
            PROC(5, kw5) PROC(6, kw6) PROC(7, kw7) PROC(8, kw8) PROC(9, kw9)
            if (tid == 0) {
                keepw[0] = kw0; keepw[1] = kw1; keepw[2] = kw2; keepw[3] = kw3;
                keepw[4] = kw4; keepw[5] = kw5; keepw[6] = kw6; keepw[7] = kw7;
                keepw[8] = kw8; keepw[9] = kw9;
            }
        }
        __syncthreads();
        for (int i = tid; i < MAXDET; i += 256)
            out[OFF_PK + (size_t)b * MAXDET + i] =
                ((keepw[i >> 5] >> (i & 31)) & 1u) ? 1.0f : 0.0f;
    }
}

extern "C" void kernel_launch(void* const* d_in, const int* in_sizes, int n_in,
                              void* d_out, int out_size, void* d_ws, size_t ws_size,
                              hipStream_t stream) {
    const float* logits  = (const float*)d_in[0];
    const float* targets = (const float*)d_in[1];
    const int*   tlen    = (const int*)d_in[2];
    float* out = (float*)d_out;
    char* ws = (char*)d_ws;
    unsigned* confbits = (unsigned*)ws;                                 // 1.613 MB
    unsigned* labels   = (unsigned*)(ws + 1612800);                     // 1.613 MB
    unsigned long long* fragg = (unsigned long long*)(ws + 3225600);    // 819200 B
    int* cntg          = (int*)(ws + 4044800);                          // 512 B
    unsigned* suppg    = (unsigned*)(ws + 4045312);                     // 230400 B
    int* flags         = (int*)(ws + 4275712);                          // 48 ints

    hipLaunchKernelGGL(kA, dim3(6300), dim3(256), 0, stream,
                       logits, confbits, labels, flags);
    hipLaunchKernelGGL(kMega, dim3(128), dim3(256), 0, stream,
                       logits, confbits, labels, fragg, cntg, suppg, flags,
                       targets, tlen, out);
}

// Round 24
// 57.997 us; speedup vs baseline: 5.0021x; 1.5289x over previous
//
#include <hip/hip_runtime.h>
#include <stdint.h>

#define BATCH   16
#define NANCH   25200
#define NCLS    80
#define REC     85
#define MAXDET  300
#define TMAX    50
#define NBUCKET 2048
#define FIN     512
#define WREG    400              // per-wave cand region (E~305, +6 sigma)
#define RSTRIDE 12               // words per supp row (10 used, 48B aligned)
#define SUPW    (MAXDET*RSTRIDE) // 3600 words per batch

// output offsets (floats)
#define OFF_PB 0
#define OFF_PS 19200
#define OFF_PL 24000
#define OFF_PK 28800
#define OFF_TB 33600
#define OFF_TS 36800
#define OFF_TL 37600
#define OFF_TV 38400

__device__ __forceinline__ float opaque_f(float x) { asm volatile("" : "+v"(x)); return x; }

// ---- Kernel A: score+label, obj-gated (conf>0.8 requires obj>0.8) ----
__global__ __launch_bounds__(256) void kA(const float* __restrict__ logits,
                                          unsigned* __restrict__ confout,
                                          unsigned* __restrict__ labout) {
    const int wid  = (blockIdx.x * 256 + threadIdx.x) >> 6;
    const int lane = threadIdx.x & 63;
    const int t    = lane >> 2;
    const int j    = lane & 3;
    const int a    = wid * 16 + t;
    const float obj = logits[(size_t)a * REC + 4];
    unsigned cf = 0u;
    if (obj > 0.8f) {
        const float* cls = logits + (size_t)a * REC + 5 + j * 20;
        float v[20];
#pragma unroll
        for (int i = 0; i < 5; ++i) {
            float4 q = *(const float4*)(cls + 4 * i);
            v[4*i+0] = q.x; v[4*i+1] = q.y; v[4*i+2] = q.z; v[4*i+3] = q.w;
        }
        float m = v[0];
#pragma unroll
        for (int i = 1; i < 20; ++i) m = fmaxf(m, v[i]);
        m = fmaxf(m, __shfl_xor(m, 1));
        m = fmaxf(m, __shfl_xor(m, 2));
        int lc = 255;
#pragma unroll
        for (int i = 0; i < 20; ++i) lc = min(lc, (v[i] == m) ? (j * 20 + i) : 255);
        lc = min(lc, __shfl_xor(lc, 1));
        lc = min(lc, __shfl_xor(lc, 2));
        const float conf = obj * m;                           // exact: single multiply
        cf = (conf > 0.8f) ? __float_as_uint(conf) : 0u;
        if (j == 0) labout[a] = (unsigned)lc;
    }
    if (j == 0) confout[a] = cf;
}

// ---- kSel: single-pass compact-all -> LDS hist -> filter -> sort -> gather ----
__global__ __launch_bounds__(1024) void kSel(const float* __restrict__ logits,
                                             const unsigned* __restrict__ confbits,
                                             const unsigned* __restrict__ labels,
                                             const float* __restrict__ targets,
                                             const int* __restrict__ tlen,
                                             float* __restrict__ out) {
    __shared__ unsigned long long cand[16 * WREG];   // 51.2 KB, per-wave regions
    __shared__ unsigned hist[NBUCKET];
    __shared__ unsigned long long fin[FIN];
    __shared__ unsigned long long srt[MAXDET];
    __shared__ int wcnts[16];
    __shared__ int sTb, sCnt;
    const int b = blockIdx.x;
    const int tid = threadIdx.x;
    const int lane = tid & 63;
    const int w = tid >> 6;

    // ---- targets fold ----
    if (tid >= 512 && tid < 512 + TMAX) {
        int t = tid - 512;
        bool is64 = (tlen[1] == 0) && (tlen[3] == 0) && (tlen[5] == 0);
        int len = is64 ? tlen[2 * b] : tlen[b];
        const float* r = targets + ((size_t)b * TMAX + t) * 6;
        float cx = r[0], cy = r[1], wd = r[2], h = r[3], sc = r[4], lb = r[5];
        float hw = opaque_f(wd * 0.5f);
        float hh = opaque_f(h * 0.5f);
        size_t o = (size_t)b * TMAX + t;
        out[OFF_TB + o * 4 + 0] = cx - hw;
        out[OFF_TB + o * 4 + 1] = cy - hh;
        out[OFF_TB + o * 4 + 2] = cx + hw;
        out[OFF_TB + o * 4 + 3] = cy + hh;
        out[OFF_TS + o] = sc;
        out[OFF_TL + o] = (float)(int)lb;
        out[OFF_TV + o] = (t < len) ? 1.0f : 0.0f;
    }

    for (int i = tid; i < NBUCKET; i += 1024) hist[i] = 0u;
    if (tid < MAXDET) srt[tid] = 0ull;
    if (tid == 0) sCnt = 0;
    __syncthreads();

    // ---- single global pass: compact ALL conf>0 into per-wave regions ----
    const uint4* cb4 = (const uint4*)(confbits + (size_t)b * NANCH);
    int wcnt = 0;                                    // wave-uniform private count
    for (int i = tid; i < NANCH / 4; i += 1024) {
        uint4 u = cb4[i];
        unsigned wsv[4] = {u.x, u.y, u.z, u.w};
#pragma unroll
        for (int c = 0; c < 4; ++c) {
            unsigned bits = wsv[c];
            bool pass = (bits != 0u);
            unsigned long long mk = __ballot(pass);
            if (pass) {
                int p = wcnt + __popcll(mk & ((1ull << lane) - 1ull));
                if (p < WREG)
                    cand[w * WREG + p] = ((unsigned long long)bits << 32) |
                                         (unsigned)(0xFFFFFFFFu - (unsigned)(i * 4 + c));
            }
            wcnt += (int)__popcll(mk);
        }
    }
    if (lane == 0 && w < 16) wcnts[w] = (wcnt < WREG) ? wcnt : WREG;
    __syncthreads();

    // ---- hist from LDS-resident candidates (~4885 items) ----
    for (int s = tid; s < 16 * WREG; s += 1024) {
        int rw = s / WREG, idx = s - rw * WREG;
        if (idx < wcnts[rw]) {
            unsigned bits = (unsigned)(cand[s] >> 32);
            unsigned bk = (bits - 0x3F4CCCCDu) >> 11;
            if (bk > NBUCKET - 1u) bk = NBUCKET - 1u;
            atomicAdd(&hist[bk], 1u);
        }
    }
    __syncthreads();

    // ---- threshold bucket tb, wave 0 ----
    if (tid < 64) {
        const int l = tid;
        unsigned sup = 0u;
        for (int j = 0; j < 32; ++j) sup += hist[l * 32 + j];
        unsigned ss = sup;
        for (int off = 1; off < 64; off <<= 1) {
            unsigned v = __shfl_down(ss, off);
            ss += (l + off < 64) ? v : 0u;
        }
        bool ge = ss >= MAXDET;
        unsigned long long mask = __ballot(ge);
        int sstar = (mask == 0ull) ? 0 : (63 - __clzll(mask));
        unsigned tail = (sstar < 63) ? __shfl(ss, sstar + 1) : 0u;
        unsigned h = (l < 32) ? hist[sstar * 32 + l] : 0u;
        unsigned s2 = h;
        for (int off = 1; off < 32; off <<= 1) {
            unsigned v = __shfl_down(s2, off);
            s2 += (l + off < 32) ? v : 0u;
        }
        bool ge2 = (l < 32) && (s2 + tail >= MAXDET);
        unsigned long long m2 = __ballot(ge2);
        int lstar = (m2 == 0ull) ? 0 : (63 - __clzll(m2));
        if (l == 0) sTb = sstar * 32 + lstar;
    }
    __syncthreads();

    // ---- filter cand >= tb into fin (few hits -> cheap atomics) ----
    const int tb = sTb;
    for (int s = tid; s < 16 * WREG; s += 1024) {
        int rw = s / WREG, idx = s - rw * WREG;
        bool pass = false;
        unsigned long long k = 0ull;
        if (idx < wcnts[rw]) {
            k = cand[s];
            unsigned bits = (unsigned)(k >> 32);
            unsigned bk = (bits - 0x3F4CCCCDu) >> 11;
            if (bk > NBUCKET - 1u) bk = NBUCKET - 1u;
            pass = ((int)bk >= tb);
        }
        unsigned long long mk = __ballot(pass);
        if (mk) {
            int base = 0;
            if (lane == 0) base = atomicAdd(&sCnt, (int)__popcll(mk));
            base = __shfl(base, 0);
            if (pass) {
                int p = base + __popcll(mk & ((1ull << lane) - 1ull));
                if (p < FIN) fin[p] = k;
            }
        }
    }
    __syncthreads();
    const int fc = (sCnt < FIN) ? sCnt : FIN;

    // ---- rank-scatter sort (order-independent; keys unique) ----
    if (tid < fc) {
        unsigned long long k = fin[tid];
        int r = 0;
        for (int j = 0; j < fc; ++j) r += (fin[j] > k) ? 1 : 0;
        if (r < MAXDET) srt[r] = k;
    }
    __syncthreads();

    // ---- gather top-300 ----
    if (tid < MAXDET) {
        unsigned long long key = srt[tid];
        float score = __uint_as_float((unsigned)(key >> 32));
        unsigned n = 0xFFFFFFFFu - (unsigned)(key & 0xFFFFFFFFull);
        if (n >= NANCH) n = 0;
        const size_t ga = (size_t)b * NANCH + n;
        float4 bq = *(const float4*)(logits + ga * REC);
        unsigned lab = labels[ga];
        float hw = opaque_f(bq.z * 0.5f);  // block FMA contraction: match XLA rounding
        float hh = opaque_f(bq.w * 0.5f);
        float x1 = bq.x - hw, y1 = bq.y - hh, x2 = bq.x + hw, y2 = bq.y + hh;
        size_t o = (size_t)(b * MAXDET + tid);
        out[OFF_PB + o * 4 + 0] = x1;
        out[OFF_PB + o * 4 + 1] = y1;
        out[OFF_PB + o * 4 + 2] = x2;
        out[OFF_PB + o * 4 + 3] = y2;
        out[OFF_PS + o] = score;
        out[OFF_PL + o] = (float)lab;
    }
}

// ---- kSup: suppression bitmatrix, NEGATED, stride-12, 8 blocks/batch ----
__global__ __launch_bounds__(256) void kSup(const float* __restrict__ out,
                                            unsigned* __restrict__ suppg) {
    __shared__ float4 sb[MAXDET];
    __shared__ float sar[MAXDET];
    const int b = blockIdx.x >> 3;
    const int s = blockIdx.x & 7;
    const int tid = threadIdx.x;
    const int lane = tid & 63;
    const int w = tid >> 6;
    const float4* boxes = (const float4*)(out + OFF_PB) + (size_t)b * MAXDET;
    for (int t = tid; t < MAXDET; t += 256) {
        float4 q = boxes[t];
        sb[t] = q;
        sar[t] = (q.z - q.x) * (q.w - q.y);       // same floats as reference area
    }
    __syncthreads();
    const int i0 = s * 38;
    const int i1 = min(i0 + 38, MAXDET);
    unsigned* sg = suppg + (size_t)b * SUPW;
    for (int i = i0 + w; i < i1; i += 4) {
        float4 bi = sb[i];
        float ai = sar[i];
#pragma unroll
        for (int c = 0; c < 5; ++c) {
            int j = c * 64 + lane;
            bool pass = false;
            if (j < MAXDET && j > i) {
                float4 bj = sb[j];
                float aj = sar[j];
                float ltx = fmaxf(bi.x, bj.x);
                float lty = fmaxf(bi.y, bj.y);
                float rbx = fminf(bi.z, bj.z);
                float rby = fminf(bi.w, bj.w);
                float wx = fmaxf(rbx - ltx, 0.0f);
                float wy = fmaxf(rby - lty, 0.0f);
                float inter = wx * wy;
                float iou = inter / (ai + aj - inter + 1e-9f);  // left-to-right
                pass = (iou > 0.4f);
            }
            unsigned long long mk = __ballot(pass);
            if (lane == 0)  sg[i * RSTRIDE + 2 * c]     = ~(unsigned)mk;          // negated
            if (lane == 32) sg[i * RSTRIDE + 2 * c + 1] = ~(unsigned)(mk >> 32);  // negated
        }
    }
}

// ---- kScan: ctz-driven scan — only KEPT rows touch LDS ----
#define PROC(C, KWC)                                                   \
    {                                                                  \
        unsigned todo = KWC;                                           \
        while (todo) {                                                 \
            int i2 = __ffs(todo) - 1;                                  \
            const uint4 a  = s4[(C * 32 + i2) * 3 + 0];                \
            const uint4 bq = s4[(C * 32 + i2) * 3 + 1];                \
            const uint4 cq = s4[(C * 32 + i2) * 3 + 2];                \
            kw0 &= a.x;  kw1 &= a.y;  kw2 &= a.z;  kw3 &= a.w;         \
            kw4 &= bq.x; kw5 &= bq.y; kw6 &= bq.z; kw7 &= bq.w;        \
            kw8 &= cq.x; kw9 &= cq.y;                                  \
            unsigned long long done = ((unsigned long long)2 << i2) - 1ull; \
            todo = KWC & ~(unsigned)done;                              \
        }                                                              \
    }

__global__ __launch_bounds__(512) void kScan(const unsigned* __restrict__ suppg,
                                             float* __restrict__ out) {
    __shared__ __align__(16) unsigned supp[SUPW];
    __shared__ unsigned keepw[10];
    const int b = blockIdx.x;
    const int tid = threadIdx.x;
    const uint4* g4 = (const uint4*)(suppg + (size_t)b * SUPW);
    uint4* l4 = (uint4*)supp;
    for (int t = tid; t < SUPW / 4; t += 512) l4[t] = g4[t];
    __syncthreads();
    if (tid < 64) {
        const uint4* s4 = (const uint4*)supp;
        unsigned kw0 = ~0u, kw1 = ~0u, kw2 = ~0u, kw3 = ~0u, kw4 = ~0u;
        unsigned kw5 = ~0u, kw6 = ~0u, kw7 = ~0u, kw8 = ~0u, kw9 = 0xFFFu;
        PROC(0, kw0) PROC(1, kw1) PROC(2, kw2) PROC(3, kw3) PROC(4, kw4)
        PROC(5, kw5) PROC(6, kw6) PROC(7, kw7) PROC(8, kw8) PROC(9, kw9)
        if (tid == 0) {
            keepw[0] = kw0; keepw[1] = kw1; keepw[2] = kw2; keepw[3] = kw3;
            keepw[4] = kw4; keepw[5] = kw5; keepw[6] = kw6; keepw[7] = kw7;
            keepw[8] = kw8; keepw[9] = kw9;
        }
    }
    __syncthreads();
    if (tid < MAXDET)
        out[OFF_PK + (size_t)b * MAXDET + tid] =
            ((keepw[tid >> 5] >> (tid & 31)) & 1u) ? 1.0f : 0.0f;
}

extern "C" void kernel_launch(void* const* d_in, const int* in_sizes, int n_in,
                              void* d_out, int out_size, void* d_ws, size_t ws_size,
                              hipStream_t stream) {
    const float* logits  = (const float*)d_in[0];
    const float* targets = (const float*)d_in[1];
    const int*   tlen    = (const int*)d_in[2];
    float* out = (float*)d_out;
    char* ws = (char*)d_ws;
    unsigned* confbits = (unsigned*)ws;                                 // 403200 u32
    unsigned* labels   = (unsigned*)(ws + (size_t)BATCH * NANCH * 4);   // 403200 u32
    unsigned* suppg    = (unsigned*)(ws + (size_t)BATCH * NANCH * 8);   // 16*3600 u32

    hipLaunchKernelGGL(kA, dim3(6300), dim3(256), 0, stream, logits, confbits, labels);
    hipLaunchKernelGGL(kSel, dim3(BATCH), dim3(1024), 0, stream,
                       logits, confbits, labels, targets, tlen, out);
    hipLaunchKernelGGL(kSup, dim3(BATCH * 8), dim3(256), 0, stream, out, suppg);
    hipLaunchKernelGGL(kScan, dim3(BATCH), dim3(512), 0, stream, suppg, out);
}